// Round 23
// baseline (495.082 us; speedup 1.0000x reference)
//
#include <hip/hip_runtime.h>
#include <cstddef>

#define Cc 96
#define CH 384
#define Mtok 262144   // B*H*W = 16*128*128
#define Mi   16384    // tokens per image

typedef unsigned short us8 __attribute__((ext_vector_type(8)));
typedef float f8 __attribute__((ext_vector_type(8)));
typedef short s8v __attribute__((ext_vector_type(8)));
typedef float f4v __attribute__((ext_vector_type(4)));

static __device__ __forceinline__ float b2f(unsigned short s){
  union { unsigned u; float f; } v; v.u = ((unsigned)s) << 16; return v.f;
}
static __device__ __forceinline__ unsigned short f2b(float f){
  union { float f; unsigned u; } v; v.f = f;
  unsigned r = v.u + 0x7fffu + ((v.u >> 16) & 1u);
  return (unsigned short)(r >> 16);
}

// ---------------- K0a: transpose dw_w [c][tap] -> wt_t [tap][c] ----------------
__global__ __launch_bounds__(64) void k_wprep(const float* __restrict__ dww,
    float* __restrict__ wt_t){
  int i = blockIdx.x*64 + threadIdx.x;   // i = tap*CH + c
  if (i < 9*CH){
    int tap = i / CH, c = i - tap*CH;
    wt_t[i] = dww[c*9 + tap];
  }
}

// ---------------- K0b: pack fc2_w [384][96] f32 -> bf16 MFMA b-frag layout ----
__global__ __launch_bounds__(256) void k_wprep2(const float* __restrict__ fc2w,
    unsigned short* __restrict__ Bp){
  int i = blockIdx.x*256 + threadIdx.x;   // < 6*12*64*8 = 36864
  int j = i & 7;
  int t = i >> 3;
  int l = t & 63;
  int u = t >> 6;          // 0..71
  int ks = u % 12, nt = u / 12;
  int k   = ks*32 + (l>>4)*8 + j;
  int col = nt*16 + (l&15);
  Bp[i] = f2b(fc2w[(size_t)k*96 + col]);
}

// ---------------- K0c: pack fc1_w [96][384] f32 -> bf16 MFMA b-frag layout ----
__global__ __launch_bounds__(256) void k_wprep1(const float* __restrict__ fc1w,
    unsigned short* __restrict__ Bp1){
  int i = blockIdx.x*256 + threadIdx.x;   // < 24*3*64*8 = 36864
  int j = i & 7;
  int t = i >> 3;
  int l = t & 63;
  int u = t >> 6;          // 0..71
  int ks = u % 3, nt = u / 3;
  int k   = ks*32 + (l>>4)*8 + j;
  int col = nt*16 + (l&15);
  Bp1[i] = f2b(fc1w[(size_t)k*CH + col]);
}

// ---------------- K2: FUSED fc1 GEMM (MFMA) + gate-H + H-shift blend -> hid ---
__global__ __launch_bounds__(320) void k_fc1f(const float* __restrict__ x,
    const float* __restrict__ gh_w, const float* __restrict__ gh_b,
    const unsigned short* __restrict__ Bp1, const float* __restrict__ fc1b,
    unsigned short* __restrict__ hid, int base, int Mloc){
  __shared__ unsigned short A[80][100];    // 16000 B, persists
  __shared__ unsigned short Y[80][104];    // 16640 B, per-chunk y1 tile
  __shared__ float wh_s[80][5];            // 1600 B
  const int tid = threadIdx.x;
  const int bid = (int)blockIdx.x;
  const int img  = bid >> 8;           // 256 blocks per image
  const int rem  = bid & 255;
  const int band = rem >> 5;           // 16-row band 0..7
  const int colg = rem & 31;           // 4-col group 0..31
  const int h0 = band*16;
  const int w0 = colg*4;
  const size_t lbase = (size_t)img*16384;       // token base within chunk

  // Phase 1: stage A (80 tile-tokens; halo rows outside image -> zeros) + gate-H
  {
    const int sr = tid>>2, sq = tid&3;   // sr = tile token 0..79
    const int r = sr>>2, cw = sr&3;
    const int h = h0 + r - 2;
    const bool valid = ((unsigned)h < 128u);
    float part[5] = {0.f,0.f,0.f,0.f,0.f};
    if (valid){
      const float* src = &x[((size_t)base + lbase + h*128 + w0 + cw)*Cc + sq*24];
      #pragma unroll
      for (int p=0;p<3;++p){
        float4 v0 = *(const float4*)&src[p*8];
        float4 v1 = *(const float4*)&src[p*8+4];
        us8 ov;
        ov[0]=f2b(v0.x); ov[1]=f2b(v0.y); ov[2]=f2b(v0.z); ov[3]=f2b(v0.w);
        ov[4]=f2b(v1.x); ov[5]=f2b(v1.y); ov[6]=f2b(v1.z); ov[7]=f2b(v1.w);
        *(us8*)&A[sr][sq*24 + p*8] = ov;
        #pragma unroll
        for (int s=0;s<5;++s){
          float4 g0 = *(const float4*)&gh_w[s*Cc + sq*24 + p*8];
          float4 g1 = *(const float4*)&gh_w[s*Cc + sq*24 + p*8 + 4];
          part[s]=fmaf(v0.x,g0.x,part[s]); part[s]=fmaf(v0.y,g0.y,part[s]);
          part[s]=fmaf(v0.z,g0.z,part[s]); part[s]=fmaf(v0.w,g0.w,part[s]);
          part[s]=fmaf(v1.x,g1.x,part[s]); part[s]=fmaf(v1.y,g1.y,part[s]);
          part[s]=fmaf(v1.z,g1.z,part[s]); part[s]=fmaf(v1.w,g1.w,part[s]);
        }
      }
    } else {
      us8 z = {0,0,0,0,0,0,0,0};
      #pragma unroll
      for (int p=0;p<3;++p) *(us8*)&A[sr][sq*24 + p*8] = z;
    }
    #pragma unroll
    for (int s=0;s<5;++s){
      float v = part[s];
      v += __shfl_xor(v, 1, 64);
      v += __shfl_xor(v, 2, 64);
      part[s] = v;
    }
    if (sq==0 && valid){
      float l[5];
      #pragma unroll
      for (int s=0;s<5;++s) l[s] = part[s] + gh_b[s];
      float mx = fmaxf(fmaxf(fmaxf(l[0],l[1]),fmaxf(l[2],l[3])),l[4]);
      float sum=0.f;
      #pragma unroll
      for (int s=0;s<5;++s){ l[s]=__expf(l[s]-mx); sum+=l[s]; }
      float inv=1.f/sum;
      #pragma unroll
      for (int s=0;s<5;++s) wh_s[sr][s] = l[s]*inv;
    }
  }
  __syncthreads();

  // Role constants
  const int wv = tid>>6, l = tid&63;
  const int row16 = l&15, g = l>>4;
  const int tl = tid>>2, q = tid&3;        // blend role (tid<256)
  const int it = (2 + (tl>>2))*4 + (tl&3); // tile token index (rows 2..17)
  const int hh = h0 + (tl>>2);
  float swgt[5];
  unsigned short* o = nullptr;
  if (tid < 256){
    #pragma unroll
    for (int i=0;i<5;++i){
      int h2 = hh - (i-2);
      swgt[i] = ((unsigned)h2 < 128u) ? wh_s[it][i] : 0.f;
    }
    o = &hid[(lbase + hh*128 + w0 + (tl&3))*CH];
  }

  // Chunk loop: 4 chunks x 96 cols
  #pragma unroll 1
  for (int chunk=0;chunk<4;++chunk){
    f4v acc[6];
    #pragma unroll
    for (int j=0;j<6;++j) acc[j] = (f4v){0.f,0.f,0.f,0.f};
    #pragma unroll
    for (int ks=0;ks<3;++ks){
      s8v a = *(const s8v*)&A[wv*16 + row16][ks*32 + g*8];
      #pragma unroll
      for (int j=0;j<6;++j){
        s8v b = *(const s8v*)&Bp1[((size_t)((chunk*6+j)*3+ks)*64 + l)*8];
        acc[j] = __builtin_amdgcn_mfma_f32_16x16x32_bf16(a, b, acc[j], 0, 0, 0);
      }
    }
    __syncthreads();   // prior blend done reading Y
    #pragma unroll
    for (int j=0;j<6;++j){
      #pragma unroll
      for (int r=0;r<4;++r){
        Y[wv*16 + g*4 + r][j*16 + row16] = f2b(acc[j][r]);
      }
    }
    __syncthreads();
    if (tid < 256){
      const int c0 = chunk*96 + q*24;
      float acc2[24];
      #pragma unroll
      for (int j=0;j<24;++j) acc2[j] = fc1b[c0+j];
      #pragma unroll
      for (int i=0;i<5;++i){
        if (swgt[i] != 0.f){
          const unsigned short* yr = &Y[it - 4*(i-2)][q*24];
          #pragma unroll
          for (int p=0;p<3;++p){
            us8 v = *(const us8*)&yr[p*8];
            #pragma unroll
            for (int j=0;j<8;++j) acc2[p*8+j] = fmaf(swgt[i], b2f(v[j]), acc2[p*8+j]);
          }
        }
      }
      #pragma unroll
      for (int p=0;p<3;++p){
        us8 ov;
        #pragma unroll
        for (int j=0;j<8;++j) ov[j] = f2b(acc2[p*8+j]);
        *(us8*)&o[c0 + p*8] = ov;
      }
    }
  }
}

// ---------------- K3: dwconv3x3 + bias + fast GELU + gate-W -> hid2, ww -------
// 512 thr = 64 token-QUADS over TWO h-rows (256 tokens/block). Halving per-row
// halo amplification (4 rows read / 2 rows produced vs 3/1) and both rows'
// halos hit the same CU's L1/L2. Per-thread code identical to r22.
__global__ __launch_bounds__(512) void k_dw(const unsigned short* __restrict__ hid,
    const float* __restrict__ wt_t, const float* __restrict__ dwb,
    const float* __restrict__ gww, const float* __restrict__ gwb,
    unsigned short* __restrict__ hid2, float* __restrict__ ww, int Mloc){
  const int tid = threadIdx.x;
  const int m0 = (int)blockIdx.x*256;
  const int p  = tid>>3, cg = tid&7;
  const int m  = m0 + 4*p;                // tokens m..m+3, same h row (w mult of 4)
  const int h = (m>>7)&127, w = m&127;
  bool hok[3];
  #pragma unroll
  for (int k=0;k<3;++k) hok[k] = ((unsigned)(h+k-1) < 128u);
  const bool cmok = (w > 0);        // column w-1
  const bool cpok = (w <= 123);     // column w+4

  float part[4][5];
  #pragma unroll
  for (int t=0;t<4;++t)
    #pragma unroll
    for (int s=0;s<5;++s) part[t][s] = 0.f;

  #pragma unroll 1
  for (int cc=0;cc<6;++cc){
    const int c = cg*8 + cc*64;
    float acc[4][8];
    {
      f8 bias = *(const f8*)&dwb[c];
      #pragma unroll
      for (int t=0;t<4;++t)
        #pragma unroll
        for (int j=0;j<8;++j) acc[t][j] = bias[j];
    }
    #pragma unroll
    for (int kh=0;kh<3;++kh){
      if (!hok[kh]) continue;
      us8 cv[6];
      {
        const unsigned short* rr = &hid[(size_t)(m + (kh-1)*128)*CH + c];
        us8 z = {0,0,0,0,0,0,0,0};
        cv[0] = cmok ? *(const us8*)(rr - CH) : z;
        cv[1] = *(const us8*)rr;
        cv[2] = *(const us8*)(rr + CH);
        cv[3] = *(const us8*)(rr + 2*CH);
        cv[4] = *(const us8*)(rr + 3*CH);
        cv[5] = cpok ? *(const us8*)(rr + 4*CH) : z;
      }
      #pragma unroll
      for (int kw=0;kw<3;++kw){
        f8 wf = *(const f8*)&wt_t[(kh*3+kw)*CH + c];
        #pragma unroll
        for (int t=0;t<4;++t)
          #pragma unroll
          for (int j=0;j<8;++j)
            acc[t][j] = fmaf(b2f(cv[kw+t][j]), wf[j], acc[t][j]);
      }
    }
    float gv[4][8];
    #pragma unroll
    for (int t=0;t<4;++t){
      us8 ov;
      #pragma unroll
      for (int j=0;j<8;++j){
        float a = acc[t][j];
        float e = __expf(-a*(1.5957691216f + 0.0713548996f*a*a));
        gv[t][j] = a*__builtin_amdgcn_rcpf(1.f + e);
        ov[j] = f2b(gv[t][j]);
      }
      *(us8*)&hid2[(size_t)(m+t)*CH + c] = ov;
    }
    #pragma unroll
    for (int s=0;s<5;++s){
      f8 gw = *(const f8*)&gww[s*CH + c];
      #pragma unroll
      for (int t=0;t<4;++t)
        #pragma unroll
        for (int j=0;j<8;++j)
          part[t][s] = fmaf(gv[t][j], gw[j], part[t][s]);
    }
  }
  #pragma unroll
  for (int t=0;t<4;++t){
    #pragma unroll
    for (int s=0;s<5;++s){
      float v = part[t][s];
      v += __shfl_xor(v, 1, 64);
      v += __shfl_xor(v, 2, 64);
      v += __shfl_xor(v, 4, 64);
      part[t][s] = v;
    }
  }
  if (cg==0){
    #pragma unroll
    for (int t=0;t<4;++t){
      float lg[5];
      #pragma unroll
      for (int s=0;s<5;++s) lg[s] = part[t][s] + gwb[s];
      float mx = fmaxf(fmaxf(fmaxf(lg[0],lg[1]),fmaxf(lg[2],lg[3])),lg[4]);
      float sum=0.f;
      #pragma unroll
      for (int s=0;s<5;++s){ lg[s]=__expf(lg[s]-mx); sum+=lg[s]; }
      float inv=1.f/sum;
      #pragma unroll
      for (int s=0;s<5;++s) ww[(size_t)s*Mloc + m + t] = lg[s]*inv;
    }
  }
}

// ---------------- K4: FUSED fc2 GEMM (MFMA) + W-shift blend -> out (f32) ------
__global__ __launch_bounds__(320) void k_fc2f(const unsigned short* __restrict__ hid2,
    const float* __restrict__ ww, const unsigned short* __restrict__ Bp,
    const float* __restrict__ fc2b, float* __restrict__ out,
    int base, int Mloc){
  __shared__ unsigned short A[80][100];    // 16000 B (per-chunk hid2 tile)
  __shared__ unsigned short Y[80][104];    // 16640 B (y tile, 96 cols used)
  const int tid = threadIdx.x;
  const int m0 = (int)blockIdx.x*64;       // interior token base
  const int w0 = m0 & 127;                 // 0 or 64
  const int rowbase = m0 - w0;             // token of w=0 in this h-row

  const int wv = tid>>6, l = tid&63;
  const int row16 = l&15, g = l>>4;
  const int srow = tid>>2, ssq = tid&3;    // staging role: row 0..79, 24-col q
  const int swtok = w0 - 2 + srow;         // tile row -> w coordinate
  const bool svalid = (srow < 68) && ((unsigned)swtok < 128u);
  const unsigned short* ssrc = svalid ?
      &hid2[(size_t)(rowbase + swtok)*CH + ssq*24] : nullptr;

  f4v acc[6];
  #pragma unroll
  for (int j=0;j<6;++j) acc[j] = (f4v){0.f,0.f,0.f,0.f};

  #pragma unroll 1
  for (int chunk=0;chunk<4;++chunk){
    // stage A chunk
    if (svalid){
      #pragma unroll
      for (int p=0;p<3;++p)
        *(us8*)&A[srow][ssq*24 + p*8] = *(const us8*)&ssrc[chunk*96 + p*8];
    } else {
      us8 z = {0,0,0,0,0,0,0,0};
      #pragma unroll
      for (int p=0;p<3;++p) *(us8*)&A[srow][ssq*24 + p*8] = z;
    }
    __syncthreads();
    #pragma unroll
    for (int ks=0;ks<3;++ks){
      s8v a = *(const s8v*)&A[wv*16 + row16][ks*32 + g*8];
      #pragma unroll
      for (int nt=0;nt<6;++nt){
        s8v b = *(const s8v*)&Bp[((size_t)(nt*12 + chunk*3 + ks)*64 + l)*8];
        acc[nt] = __builtin_amdgcn_mfma_f32_16x16x32_bf16(a, b, acc[nt], 0, 0, 0);
      }
    }
    __syncthreads();   // done reading A before next chunk overwrites
  }

  // write y tile to LDS (bf16, same rounding as old global y)
  #pragma unroll
  for (int nt=0;nt<6;++nt){
    #pragma unroll
    for (int r=0;r<4;++r){
      Y[wv*16 + g*4 + r][nt*16 + row16] = f2b(acc[nt][r]);
    }
  }
  __syncthreads();

  // blend phase (first 256 threads): token t 0..63, 24-col quarter q
  if (tid < 256){
    const int t = tid>>2, q = tid&3;
    const int ml = m0 + t;
    const int gm = base + ml;
    const int wp = w0 + t;
    float swgt[5];
    #pragma unroll
    for (int i=0;i<5;++i){
      int w2 = wp - (i-2);
      swgt[i] = ((unsigned)w2 < 128u) ? ww[(size_t)i*Mloc + ml] : 0.f;
    }
    const int c0 = q*24;
    float acc2[24];
    #pragma unroll
    for (int j=0;j<24;++j) acc2[j] = fc2b[c0+j];
    #pragma unroll
    for (int i=0;i<5;++i){
      if (swgt[i] != 0.f){
        const unsigned short* yr = &Y[(t+2) - (i-2)][c0];
        #pragma unroll
        for (int p=0;p<3;++p){
          us8 v = *(const us8*)&yr[p*8];
          #pragma unroll
          for (int j=0;j<8;++j) acc2[p*8+j] = fmaf(swgt[i], b2f(v[j]), acc2[p*8+j]);
        }
      }
    }
    float* o = &out[(size_t)gm*96 + c0];
    #pragma unroll
    for (int p=0;p<6;++p)
      *(float4*)&o[p*4] = make_float4(acc2[p*4],acc2[p*4+1],acc2[p*4+2],acc2[p*4+3]);
  }
}

extern "C" void kernel_launch(void* const* d_in, const int* in_sizes, int n_in,
                              void* d_out, int out_size, void* d_ws, size_t ws_size,
                              hipStream_t stream) {
  const float* x     = (const float*)d_in[0];
  const float* fc1_w = (const float*)d_in[3];
  const float* fc1_b = (const float*)d_in[4];
  const float* dw_w  = (const float*)d_in[5];
  const float* dw_b  = (const float*)d_in[6];
  const float* fc2_w = (const float*)d_in[7];
  const float* fc2_b = (const float*)d_in[8];
  const float* gh_w  = (const float*)d_in[9];
  const float* gh_b  = (const float*)d_in[10];
  const float* gw_w  = (const float*)d_in[11];
  const float* gw_b  = (const float*)d_in[12];
  float* out = (float*)d_out;

  // ws: wt_t 13824 B | Bp2 73728 B | Bp1 73728 B | chunk scratch
  float* wt_t = (float*)d_ws;
  unsigned short* Bp  = (unsigned short*)((char*)d_ws + 13824);
  unsigned short* Bp1 = (unsigned short*)((char*)d_ws + 13824 + 73728);
  char*  wsc  = (char*)d_ws + 13824 + 73728 + 73728;
  size_t ws_rem = (ws_size > 161280) ? ws_size - 161280 : 0;

  k_wprep<<<(9*CH + 63)/64, 64, 0, stream>>>(dw_w, wt_t);
  k_wprep2<<<144, 256, 0, stream>>>(fc2_w, Bp);
  k_wprep1<<<144, 256, 0, stream>>>(fc1_w, Bp1);

  // per-image: ww 5*Mi*4 | hid Mi*384*2 | hid2 Mi*384*2
  const size_t pi = (size_t)5*Mi*4 + (size_t)Mi*CH*2*2;
  int NI = (int)(ws_rem / pi);
  if (NI < 1) NI = 1;
  if (NI > 16) NI = 16;

  for (int b0 = 0; b0 < 16; b0 += NI) {
    int nb = (16 - b0 < NI) ? (16 - b0) : NI;
    int Mloc = nb * Mi;
    int base = b0 * Mi;
    float* ww = (float*)wsc;
    unsigned short* hid  = (unsigned short*)(ww + (size_t)5*Mloc);
    unsigned short* hid2 = hid + (size_t)Mloc*CH;
    k_fc1f<<<Mloc/64, 320, 0, stream>>>(x, gh_w, gh_b, Bp1, fc1_b, hid, base, Mloc);
    k_dw<<<Mloc/256, 512, 0, stream>>>(hid, wt_t, dw_b, gw_w, gw_b, hid2, ww, Mloc);
    k_fc2f<<<Mloc/64, 320, 0, stream>>>(hid2, ww, Bp, fc2_b, out, base, Mloc);
  }
}

// Round 24
// 478.711 us; speedup vs baseline: 1.0342x; 1.0342x over previous
//
#include <hip/hip_runtime.h>
#include <cstddef>

#define Cc 96
#define CH 384
#define Mtok 262144   // B*H*W = 16*128*128
#define Mi   16384    // tokens per image

typedef unsigned short us8 __attribute__((ext_vector_type(8)));
typedef float f8 __attribute__((ext_vector_type(8)));
typedef short s8v __attribute__((ext_vector_type(8)));
typedef float f4v __attribute__((ext_vector_type(4)));

static __device__ __forceinline__ float b2f(unsigned short s){
  union { unsigned u; float f; } v; v.u = ((unsigned)s) << 16; return v.f;
}
static __device__ __forceinline__ unsigned short f2b(float f){
  union { float f; unsigned u; } v; v.f = f;
  unsigned r = v.u + 0x7fffu + ((v.u >> 16) & 1u);
  return (unsigned short)(r >> 16);
}

// ---------------- K0a: transpose dw_w [c][tap] -> wt_t [tap][c] ----------------
__global__ __launch_bounds__(64) void k_wprep(const float* __restrict__ dww,
    float* __restrict__ wt_t){
  int i = blockIdx.x*64 + threadIdx.x;   // i = tap*CH + c
  if (i < 9*CH){
    int tap = i / CH, c = i - tap*CH;
    wt_t[i] = dww[c*9 + tap];
  }
}

// ---------------- K0b: pack fc2_w [384][96] f32 -> bf16 MFMA b-frag layout ----
__global__ __launch_bounds__(256) void k_wprep2(const float* __restrict__ fc2w,
    unsigned short* __restrict__ Bp){
  int i = blockIdx.x*256 + threadIdx.x;   // < 6*12*64*8 = 36864
  int j = i & 7;
  int t = i >> 3;
  int l = t & 63;
  int u = t >> 6;          // 0..71
  int ks = u % 12, nt = u / 12;
  int k   = ks*32 + (l>>4)*8 + j;
  int col = nt*16 + (l&15);
  Bp[i] = f2b(fc2w[(size_t)k*96 + col]);
}

// ---------------- K0c: pack fc1_w [96][384] f32 -> bf16 MFMA b-frag layout ----
__global__ __launch_bounds__(256) void k_wprep1(const float* __restrict__ fc1w,
    unsigned short* __restrict__ Bp1){
  int i = blockIdx.x*256 + threadIdx.x;   // < 24*3*64*8 = 36864
  int j = i & 7;
  int t = i >> 3;
  int l = t & 63;
  int u = t >> 6;          // 0..71
  int ks = u % 3, nt = u / 3;
  int k   = ks*32 + (l>>4)*8 + j;
  int col = nt*16 + (l&15);
  Bp1[i] = f2b(fc1w[(size_t)k*CH + col]);
}

// ---------------- K2: FUSED fc1 GEMM (MFMA) + gate-H + H-shift blend -> hid ---
__global__ __launch_bounds__(320) void k_fc1f(const float* __restrict__ x,
    const float* __restrict__ gh_w, const float* __restrict__ gh_b,
    const unsigned short* __restrict__ Bp1, const float* __restrict__ fc1b,
    unsigned short* __restrict__ hid, int base, int Mloc){
  __shared__ unsigned short A[80][100];    // 16000 B, persists
  __shared__ unsigned short Y[80][104];    // 16640 B, per-chunk y1 tile
  __shared__ float wh_s[80][5];            // 1600 B
  const int tid = threadIdx.x;
  const int bid = (int)blockIdx.x;
  const int img  = bid >> 8;           // 256 blocks per image
  const int rem  = bid & 255;
  const int band = rem >> 5;           // 16-row band 0..7
  const int colg = rem & 31;           // 4-col group 0..31
  const int h0 = band*16;
  const int w0 = colg*4;
  const size_t lbase = (size_t)img*16384;       // token base within chunk

  // Phase 1: stage A (80 tile-tokens; halo rows outside image -> zeros) + gate-H
  {
    const int sr = tid>>2, sq = tid&3;   // sr = tile token 0..79
    const int r = sr>>2, cw = sr&3;
    const int h = h0 + r - 2;
    const bool valid = ((unsigned)h < 128u);
    float part[5] = {0.f,0.f,0.f,0.f,0.f};
    if (valid){
      const float* src = &x[((size_t)base + lbase + h*128 + w0 + cw)*Cc + sq*24];
      #pragma unroll
      for (int p=0;p<3;++p){
        float4 v0 = *(const float4*)&src[p*8];
        float4 v1 = *(const float4*)&src[p*8+4];
        us8 ov;
        ov[0]=f2b(v0.x); ov[1]=f2b(v0.y); ov[2]=f2b(v0.z); ov[3]=f2b(v0.w);
        ov[4]=f2b(v1.x); ov[5]=f2b(v1.y); ov[6]=f2b(v1.z); ov[7]=f2b(v1.w);
        *(us8*)&A[sr][sq*24 + p*8] = ov;
        #pragma unroll
        for (int s=0;s<5;++s){
          float4 g0 = *(const float4*)&gh_w[s*Cc + sq*24 + p*8];
          float4 g1 = *(const float4*)&gh_w[s*Cc + sq*24 + p*8 + 4];
          part[s]=fmaf(v0.x,g0.x,part[s]); part[s]=fmaf(v0.y,g0.y,part[s]);
          part[s]=fmaf(v0.z,g0.z,part[s]); part[s]=fmaf(v0.w,g0.w,part[s]);
          part[s]=fmaf(v1.x,g1.x,part[s]); part[s]=fmaf(v1.y,g1.y,part[s]);
          part[s]=fmaf(v1.z,g1.z,part[s]); part[s]=fmaf(v1.w,g1.w,part[s]);
        }
      }
    } else {
      us8 z = {0,0,0,0,0,0,0,0};
      #pragma unroll
      for (int p=0;p<3;++p) *(us8*)&A[sr][sq*24 + p*8] = z;
    }
    #pragma unroll
    for (int s=0;s<5;++s){
      float v = part[s];
      v += __shfl_xor(v, 1, 64);
      v += __shfl_xor(v, 2, 64);
      part[s] = v;
    }
    if (sq==0 && valid){
      float l[5];
      #pragma unroll
      for (int s=0;s<5;++s) l[s] = part[s] + gh_b[s];
      float mx = fmaxf(fmaxf(fmaxf(l[0],l[1]),fmaxf(l[2],l[3])),l[4]);
      float sum=0.f;
      #pragma unroll
      for (int s=0;s<5;++s){ l[s]=__expf(l[s]-mx); sum+=l[s]; }
      float inv=1.f/sum;
      #pragma unroll
      for (int s=0;s<5;++s) wh_s[sr][s] = l[s]*inv;
    }
  }
  __syncthreads();

  // Role constants
  const int wv = tid>>6, l = tid&63;
  const int row16 = l&15, g = l>>4;
  const int tl = tid>>2, q = tid&3;        // blend role (tid<256)
  const int it = (2 + (tl>>2))*4 + (tl&3); // tile token index (rows 2..17)
  const int hh = h0 + (tl>>2);
  float swgt[5];
  unsigned short* o = nullptr;
  if (tid < 256){
    #pragma unroll
    for (int i=0;i<5;++i){
      int h2 = hh - (i-2);
      swgt[i] = ((unsigned)h2 < 128u) ? wh_s[it][i] : 0.f;
    }
    o = &hid[(lbase + hh*128 + w0 + (tl&3))*CH];
  }

  // Chunk loop: 4 chunks x 96 cols
  #pragma unroll 1
  for (int chunk=0;chunk<4;++chunk){
    f4v acc[6];
    #pragma unroll
    for (int j=0;j<6;++j) acc[j] = (f4v){0.f,0.f,0.f,0.f};
    #pragma unroll
    for (int ks=0;ks<3;++ks){
      s8v a = *(const s8v*)&A[wv*16 + row16][ks*32 + g*8];
      #pragma unroll
      for (int j=0;j<6;++j){
        s8v b = *(const s8v*)&Bp1[((size_t)((chunk*6+j)*3+ks)*64 + l)*8];
        acc[j] = __builtin_amdgcn_mfma_f32_16x16x32_bf16(a, b, acc[j], 0, 0, 0);
      }
    }
    __syncthreads();   // prior blend done reading Y
    #pragma unroll
    for (int j=0;j<6;++j){
      #pragma unroll
      for (int r=0;r<4;++r){
        Y[wv*16 + g*4 + r][j*16 + row16] = f2b(acc[j][r]);
      }
    }
    __syncthreads();
    if (tid < 256){
      const int c0 = chunk*96 + q*24;
      float acc2[24];
      #pragma unroll
      for (int j=0;j<24;++j) acc2[j] = fc1b[c0+j];
      #pragma unroll
      for (int i=0;i<5;++i){
        if (swgt[i] != 0.f){
          const unsigned short* yr = &Y[it - 4*(i-2)][q*24];
          #pragma unroll
          for (int p=0;p<3;++p){
            us8 v = *(const us8*)&yr[p*8];
            #pragma unroll
            for (int j=0;j<8;++j) acc2[p*8+j] = fmaf(swgt[i], b2f(v[j]), acc2[p*8+j]);
          }
        }
      }
      #pragma unroll
      for (int p=0;p<3;++p){
        us8 ov;
        #pragma unroll
        for (int j=0;j<8;++j) ov[j] = f2b(acc2[p*8+j]);
        *(us8*)&o[c0 + p*8] = ov;
      }
    }
  }
}

// ---------------- K3: dwconv3x3 + bias + fast GELU + gate-W -> hid2, ww -------
// 512 thr = 64 token-QUADS over TWO h-rows. bf16->f32 conversions hoisted:
// each loaded column converted to float ONCE (fcv), FMAs reuse — removes
// duplicate v_lshl work if the compiler wasn't CSE-ing b2f across taps.
__global__ __launch_bounds__(512) void k_dw(const unsigned short* __restrict__ hid,
    const float* __restrict__ wt_t, const float* __restrict__ dwb,
    const float* __restrict__ gww, const float* __restrict__ gwb,
    unsigned short* __restrict__ hid2, float* __restrict__ ww, int Mloc){
  const int tid = threadIdx.x;
  const int m0 = (int)blockIdx.x*256;
  const int p  = tid>>3, cg = tid&7;
  const int m  = m0 + 4*p;                // tokens m..m+3, same h row (w mult of 4)
  const int h = (m>>7)&127, w = m&127;
  bool hok[3];
  #pragma unroll
  for (int k=0;k<3;++k) hok[k] = ((unsigned)(h+k-1) < 128u);
  const bool cmok = (w > 0);        // column w-1
  const bool cpok = (w <= 123);     // column w+4

  float part[4][5];
  #pragma unroll
  for (int t=0;t<4;++t)
    #pragma unroll
    for (int s=0;s<5;++s) part[t][s] = 0.f;

  #pragma unroll 1
  for (int cc=0;cc<6;++cc){
    const int c = cg*8 + cc*64;
    float acc[4][8];
    {
      f8 bias = *(const f8*)&dwb[c];
      #pragma unroll
      for (int t=0;t<4;++t)
        #pragma unroll
        for (int j=0;j<8;++j) acc[t][j] = bias[j];
    }
    #pragma unroll
    for (int kh=0;kh<3;++kh){
      if (!hok[kh]) continue;
      float fcv[6][8];
      {
        const unsigned short* rr = &hid[(size_t)(m + (kh-1)*128)*CH + c];
        us8 cv[6];
        us8 z = {0,0,0,0,0,0,0,0};
        cv[0] = cmok ? *(const us8*)(rr - CH) : z;
        cv[1] = *(const us8*)rr;
        cv[2] = *(const us8*)(rr + CH);
        cv[3] = *(const us8*)(rr + 2*CH);
        cv[4] = *(const us8*)(rr + 3*CH);
        cv[5] = cpok ? *(const us8*)(rr + 4*CH) : z;
        #pragma unroll
        for (int q2=0;q2<6;++q2)
          #pragma unroll
          for (int j=0;j<8;++j) fcv[q2][j] = b2f(cv[q2][j]);
      }
      #pragma unroll
      for (int kw=0;kw<3;++kw){
        f8 wf = *(const f8*)&wt_t[(kh*3+kw)*CH + c];
        #pragma unroll
        for (int t=0;t<4;++t)
          #pragma unroll
          for (int j=0;j<8;++j)
            acc[t][j] = fmaf(fcv[kw+t][j], wf[j], acc[t][j]);
      }
    }
    float gv[4][8];
    #pragma unroll
    for (int t=0;t<4;++t){
      us8 ov;
      #pragma unroll
      for (int j=0;j<8;++j){
        float a = acc[t][j];
        float e = __expf(-a*(1.5957691216f + 0.0713548996f*a*a));
        gv[t][j] = a*__builtin_amdgcn_rcpf(1.f + e);
        ov[j] = f2b(gv[t][j]);
      }
      *(us8*)&hid2[(size_t)(m+t)*CH + c] = ov;
    }
    #pragma unroll
    for (int s=0;s<5;++s){
      f8 gw = *(const f8*)&gww[s*CH + c];
      #pragma unroll
      for (int t=0;t<4;++t)
        #pragma unroll
        for (int j=0;j<8;++j)
          part[t][s] = fmaf(gv[t][j], gw[j], part[t][s]);
    }
  }
  #pragma unroll
  for (int t=0;t<4;++t){
    #pragma unroll
    for (int s=0;s<5;++s){
      float v = part[t][s];
      v += __shfl_xor(v, 1, 64);
      v += __shfl_xor(v, 2, 64);
      v += __shfl_xor(v, 4, 64);
      part[t][s] = v;
    }
  }
  if (cg==0){
    #pragma unroll
    for (int t=0;t<4;++t){
      float lg[5];
      #pragma unroll
      for (int s=0;s<5;++s) lg[s] = part[t][s] + gwb[s];
      float mx = fmaxf(fmaxf(fmaxf(lg[0],lg[1]),fmaxf(lg[2],lg[3])),lg[4]);
      float sum=0.f;
      #pragma unroll
      for (int s=0;s<5;++s){ lg[s]=__expf(lg[s]-mx); sum+=lg[s]; }
      float inv=1.f/sum;
      #pragma unroll
      for (int s=0;s<5;++s) ww[(size_t)s*Mloc + m + t] = lg[s]*inv;
    }
  }
}

// ---------------- K4: FUSED fc2 GEMM (MFMA) + W-shift blend -> out (f32) ------
__global__ __launch_bounds__(320) void k_fc2f(const unsigned short* __restrict__ hid2,
    const float* __restrict__ ww, const unsigned short* __restrict__ Bp,
    const float* __restrict__ fc2b, float* __restrict__ out,
    int base, int Mloc){
  __shared__ unsigned short A[80][100];    // 16000 B (per-chunk hid2 tile)
  __shared__ unsigned short Y[80][104];    // 16640 B (y tile, 96 cols used)
  const int tid = threadIdx.x;
  const int m0 = (int)blockIdx.x*64;       // interior token base
  const int w0 = m0 & 127;                 // 0 or 64
  const int rowbase = m0 - w0;             // token of w=0 in this h-row

  const int wv = tid>>6, l = tid&63;
  const int row16 = l&15, g = l>>4;
  const int srow = tid>>2, ssq = tid&3;    // staging role: row 0..79, 24-col q
  const int swtok = w0 - 2 + srow;         // tile row -> w coordinate
  const bool svalid = (srow < 68) && ((unsigned)swtok < 128u);
  const unsigned short* ssrc = svalid ?
      &hid2[(size_t)(rowbase + swtok)*CH + ssq*24] : nullptr;

  f4v acc[6];
  #pragma unroll
  for (int j=0;j<6;++j) acc[j] = (f4v){0.f,0.f,0.f,0.f};

  #pragma unroll 1
  for (int chunk=0;chunk<4;++chunk){
    // stage A chunk
    if (svalid){
      #pragma unroll
      for (int p=0;p<3;++p)
        *(us8*)&A[srow][ssq*24 + p*8] = *(const us8*)&ssrc[chunk*96 + p*8];
    } else {
      us8 z = {0,0,0,0,0,0,0,0};
      #pragma unroll
      for (int p=0;p<3;++p) *(us8*)&A[srow][ssq*24 + p*8] = z;
    }
    __syncthreads();
    #pragma unroll
    for (int ks=0;ks<3;++ks){
      s8v a = *(const s8v*)&A[wv*16 + row16][ks*32 + g*8];
      #pragma unroll
      for (int nt=0;nt<6;++nt){
        s8v b = *(const s8v*)&Bp[((size_t)(nt*12 + chunk*3 + ks)*64 + l)*8];
        acc[nt] = __builtin_amdgcn_mfma_f32_16x16x32_bf16(a, b, acc[nt], 0, 0, 0);
      }
    }
    __syncthreads();   // done reading A before next chunk overwrites
  }

  // write y tile to LDS (bf16, same rounding as old global y)
  #pragma unroll
  for (int nt=0;nt<6;++nt){
    #pragma unroll
    for (int r=0;r<4;++r){
      Y[wv*16 + g*4 + r][nt*16 + row16] = f2b(acc[nt][r]);
    }
  }
  __syncthreads();

  // blend phase (first 256 threads): token t 0..63, 24-col quarter q
  if (tid < 256){
    const int t = tid>>2, q = tid&3;
    const int ml = m0 + t;
    const int gm = base + ml;
    const int wp = w0 + t;
    float swgt[5];
    #pragma unroll
    for (int i=0;i<5;++i){
      int w2 = wp - (i-2);
      swgt[i] = ((unsigned)w2 < 128u) ? ww[(size_t)i*Mloc + ml] : 0.f;
    }
    const int c0 = q*24;
    float acc2[24];
    #pragma unroll
    for (int j=0;j<24;++j) acc2[j] = fc2b[c0+j];
    #pragma unroll
    for (int i=0;i<5;++i){
      if (swgt[i] != 0.f){
        const unsigned short* yr = &Y[(t+2) - (i-2)][c0];
        #pragma unroll
        for (int p=0;p<3;++p){
          us8 v = *(const us8*)&yr[p*8];
          #pragma unroll
          for (int j=0;j<8;++j) acc2[p*8+j] = fmaf(swgt[i], b2f(v[j]), acc2[p*8+j]);
        }
      }
    }
    float* o = &out[(size_t)gm*96 + c0];
    #pragma unroll
    for (int p=0;p<6;++p)
      *(float4*)&o[p*4] = make_float4(acc2[p*4],acc2[p*4+1],acc2[p*4+2],acc2[p*4+3]);
  }
}

extern "C" void kernel_launch(void* const* d_in, const int* in_sizes, int n_in,
                              void* d_out, int out_size, void* d_ws, size_t ws_size,
                              hipStream_t stream) {
  const float* x     = (const float*)d_in[0];
  const float* fc1_w = (const float*)d_in[3];
  const float* fc1_b = (const float*)d_in[4];
  const float* dw_w  = (const float*)d_in[5];
  const float* dw_b  = (const float*)d_in[6];
  const float* fc2_w = (const float*)d_in[7];
  const float* fc2_b = (const float*)d_in[8];
  const float* gh_w  = (const float*)d_in[9];
  const float* gh_b  = (const float*)d_in[10];
  const float* gw_w  = (const float*)d_in[11];
  const float* gw_b  = (const float*)d_in[12];
  float* out = (float*)d_out;

  // ws: wt_t 13824 B | Bp2 73728 B | Bp1 73728 B | chunk scratch
  float* wt_t = (float*)d_ws;
  unsigned short* Bp  = (unsigned short*)((char*)d_ws + 13824);
  unsigned short* Bp1 = (unsigned short*)((char*)d_ws + 13824 + 73728);
  char*  wsc  = (char*)d_ws + 13824 + 73728 + 73728;
  size_t ws_rem = (ws_size > 161280) ? ws_size - 161280 : 0;

  k_wprep<<<(9*CH + 63)/64, 64, 0, stream>>>(dw_w, wt_t);
  k_wprep2<<<144, 256, 0, stream>>>(fc2_w, Bp);
  k_wprep1<<<144, 256, 0, stream>>>(fc1_w, Bp1);

  // per-image: ww 5*Mi*4 | hid Mi*384*2 | hid2 Mi*384*2
  const size_t pi = (size_t)5*Mi*4 + (size_t)Mi*CH*2*2;
  int NI = (int)(ws_rem / pi);
  if (NI < 1) NI = 1;
  if (NI > 16) NI = 16;

  for (int b0 = 0; b0 < 16; b0 += NI) {
    int nb = (16 - b0 < NI) ? (16 - b0) : NI;
    int Mloc = nb * Mi;
    int base = b0 * Mi;
    float* ww = (float*)wsc;
    unsigned short* hid  = (unsigned short*)(ww + (size_t)5*Mloc);
    unsigned short* hid2 = hid + (size_t)Mloc*CH;
    k_fc1f<<<Mloc/64, 320, 0, stream>>>(x, gh_w, gh_b, Bp1, fc1_b, hid, base, Mloc);
    k_dw<<<Mloc/256, 512, 0, stream>>>(hid, wt_t, dw_b, gw_w, gw_b, hid2, ww, Mloc);
    k_fc2f<<<Mloc/64, 320, 0, stream>>>(hid2, ww, Bp, fc2_b, out, base, Mloc);
  }
}